// Round 2
// baseline (84.543 us; speedup 1.0000x reference)
//
#include <hip/hip_runtime.h>

typedef __attribute__((ext_vector_type(8))) __bf16 bf16x8;
typedef __attribute__((ext_vector_type(4))) float f32x4;

#define NCH 16   // chunks per group: 1024 / 64
#define KC 64

__device__ __forceinline__ unsigned short f2bf(float x) {
    unsigned u = __float_as_uint(x);
    u += 0x7FFFu + ((u >> 16) & 1u);   // round-to-nearest-even
    return (unsigned short)(u >> 16);
}

// ws layout (floats): dmat[4096] | Gnn[4096] | Gaa[4096] | Rn[64] | Ra[64] | Sn[64] | Sa[64]
__global__ __launch_bounds__(512) void cl_main(const float* __restrict__ feats,
                                               float* __restrict__ ws)
{
    float* dmat = ws;
    float* Gnn  = ws + 4096;
    float* Gaa  = ws + 8192;
    float* Rn   = ws + 12288;
    float* Ra   = ws + 12352;
    float* Sn   = ws + 12416;
    float* Sa   = ws + 12480;

    const int t   = blockIdx.x;          // 0..199
    const int tid = threadIdx.x;         // 0..511
    const int grp = tid >> 8;            // K-group: 0 -> [0,1024), 1 -> [1024,2048)
    const int lt  = tid & 255;           // id within group
    const int row = lt >> 2;             // loader row 0..63
    const int q   = lt & 3;              // 4 loader lanes per row
    const int w   = lt >> 6;             // wave-in-group 0..3
    const int r16 = lt & 15;
    const int kg  = (lt & 63) >> 4;

    // [grp][buf][row][k] staging, double-buffered per group
    __shared__ __align__(16) unsigned short lN[2][2][64][64];   // 32 KB
    __shared__ __align__(16) unsigned short lA[2][2][64][64];   // 32 KB
    __shared__ float red[3 * 4096];                             // 48 KB cross-group reduce
    __shared__ float n2p[2][64], a2p[2][64];

    const float* gN = feats + (size_t)row        * 409600 + (size_t)t * 2048 + grp * 1024;
    const float* gA = feats + (size_t)(64 + row) * 409600 + (size_t)t * 2048 + grp * 1024;

    float nq = 0.f, ns = 0.f, aq = 0.f, ar = 0.f, asum = 0.f;
    f32x4 accD[4], accNN[4], accAA[4];
    const f32x4 zero = {0.f, 0.f, 0.f, 0.f};
    #pragma unroll
    for (int j = 0; j < 4; ++j) { accD[j] = zero; accNN[j] = zero; accAA[j] = zero; }

    const int swz  = (row & 7) << 3;
    const int rswz = (r16 & 7) << 3;

    float4 rNA[4], rAA[4], rNB[4], rAB[4];   // two static staging sets

#define LOAD_SET(RN, RA, c)                                            \
    {                                                                  \
        const int ko = (c) * KC;                                       \
        _Pragma("unroll")                                              \
        for (int s = 0; s < 4; ++s) {                                  \
            const int k = 4 * q + 16 * s;                              \
            RN[s] = *(const float4*)(gN + ko + k);                     \
            RA[s] = *(const float4*)(gA + ko + k);                     \
        }                                                              \
    }

#define WRITE_SET(RN, RA, buf)                                         \
    {                                                                  \
        _Pragma("unroll")                                              \
        for (int s = 0; s < 4; ++s) {                                  \
            const int k = 4 * q + 16 * s;                              \
            float4 vn = RN[s], va = RA[s];                             \
            nq += vn.x*vn.x + vn.y*vn.y + vn.z*vn.z + vn.w*vn.w;       \
            ns += vn.x + vn.y + vn.z + vn.w;                           \
            const float e = 1e-6f;                                     \
            float ax = va.x - e, ay = va.y - e, az = va.z - e, aw = va.w - e; \
            aq += ax*ax + ay*ay + az*az + aw*aw;                       \
            ar += va.x*va.x + va.y*va.y + va.z*va.z + va.w*va.w;       \
            asum += va.x + va.y + va.z + va.w;                         \
            ushort4 pn; pn.x=f2bf(vn.x); pn.y=f2bf(vn.y); pn.z=f2bf(vn.z); pn.w=f2bf(vn.w); \
            ushort4 pa; pa.x=f2bf(va.x); pa.y=f2bf(va.y); pa.z=f2bf(va.z); pa.w=f2bf(va.w); \
            *(ushort4*)&lN[grp][buf][row][k ^ swz] = pn;               \
            *(ushort4*)&lA[grp][buf][row][k ^ swz] = pa;               \
        }                                                              \
    }

#define MFMA_SET(buf)                                                  \
    {                                                                  \
        _Pragma("unroll")                                              \
        for (int ks = 0; ks < 2; ++ks) {                               \
            const int kb = ks * 32 + kg * 8;                           \
            bf16x8 aN = *(const bf16x8*)&lN[grp][buf][w*16 + r16][kb ^ rswz]; \
            bf16x8 aA = *(const bf16x8*)&lA[grp][buf][w*16 + r16][kb ^ rswz]; \
            _Pragma("unroll")                                          \
            for (int jt = 0; jt < 4; ++jt) {                           \
                bf16x8 bN = *(const bf16x8*)&lN[grp][buf][jt*16 + r16][kb ^ rswz]; \
                bf16x8 bA = *(const bf16x8*)&lA[grp][buf][jt*16 + r16][kb ^ rswz]; \
                accD[jt]  = __builtin_amdgcn_mfma_f32_16x16x32_bf16(aN, bA, accD[jt],  0, 0, 0); \
                accNN[jt] = __builtin_amdgcn_mfma_f32_16x16x32_bf16(aN, bN, accNN[jt], 0, 0, 0); \
                accAA[jt] = __builtin_amdgcn_mfma_f32_16x16x32_bf16(aA, bA, accAA[jt], 0, 0, 0); \
            }                                                          \
        }                                                              \
    }

    // prologue: chunks 0,1 in flight; stage chunk 0
    LOAD_SET(rNA, rAA, 0)
    LOAD_SET(rNB, rAB, 1)
    WRITE_SET(rNA, rAA, 0)
    __syncthreads();

    #pragma unroll 1
    for (int c = 0; c < NCH; c += 2) {
        // even chunk c: lds buf 0, staging set A free
        if (c + 2 < NCH) LOAD_SET(rNA, rAA, c + 2)
        MFMA_SET(0)
        WRITE_SET(rNB, rAB, 1)          // chunk c+1 (always exists: NCH even)
        __syncthreads();
        // odd chunk c+1: lds buf 1, staging set B free
        if (c + 3 < NCH) LOAD_SET(rNB, rAB, c + 3)
        MFMA_SET(1)
        if (c + 2 < NCH) WRITE_SET(rNA, rAA, 0)
        __syncthreads();
    }

    // per-(row,t,grp) norm partials: reduce across the 4 loader lanes
    nq   += __shfl_xor(nq, 1);   nq   += __shfl_xor(nq, 2);
    aq   += __shfl_xor(aq, 1);   aq   += __shfl_xor(aq, 2);
    ns   += __shfl_xor(ns, 1);   ns   += __shfl_xor(ns, 2);
    ar   += __shfl_xor(ar, 1);   ar   += __shfl_xor(ar, 2);
    asum += __shfl_xor(asum, 1); asum += __shfl_xor(asum, 2);
    if (q == 0) {
        n2p[grp][row] = nq;
        a2p[grp][row] = aq;
        atomicAdd(&Rn[row], nq);
        atomicAdd(&Ra[row], ar);
        atomicAdd(&Sn[row], ns);
        atomicAdd(&Sa[row], asum);
    }

    // group 1 publishes its partial accumulators
    if (grp == 1) {
        #pragma unroll
        for (int jt = 0; jt < 4; ++jt) {
            #pragma unroll
            for (int r = 0; r < 4; ++r) {
                const int ij = (w*16 + kg*4 + r) * 64 + jt*16 + r16;
                red[ij]        = accD[jt][r];
                red[4096 + ij] = accNN[jt][r];
                red[8192 + ij] = accAA[jt][r];
            }
        }
    }
    __syncthreads();

    if (grp == 0) {
        float n2v[4];
        #pragma unroll
        for (int r = 0; r < 4; ++r) {
            const int i = w*16 + kg*4 + r;
            n2v[r] = n2p[0][i] + n2p[1][i];
        }
        #pragma unroll
        for (int jt = 0; jt < 4; ++jt) {
            const int j = jt*16 + r16;
            const float a2v = a2p[0][j] + a2p[1][j];
            #pragma unroll
            for (int r = 0; r < 4; ++r) {
                const int ij = (w*16 + kg*4 + r) * 64 + j;
                float cross = accD[jt][r]  + red[ij];
                float gnn   = accNN[jt][r] + red[4096 + ij];
                float gaa   = accAA[jt][r] + red[8192 + ij];
                float dist2 = fmaxf(n2v[r] + a2v - 2.f * cross, 0.f);
                float v = fmaxf(200.f - sqrtf(dist2), 0.f);
                atomicAdd(&dmat[ij], v * v * 0.005f);   // 1/200
                atomicAdd(&Gnn[ij], gnn);
                atomicAdd(&Gaa[ij], gaa);
            }
        }
    }
#undef LOAD_SET
#undef WRITE_SET
#undef MFMA_SET
}

__global__ __launch_bounds__(256) void cl_final(const float* __restrict__ ws,
                                                float* __restrict__ out)
{
    const float* dmat = ws;
    const float* Gnn  = ws + 4096;
    const float* Gaa  = ws + 8192;
    const float* Rn   = ws + 12288;
    const float* Ra   = ws + 12352;
    const float* Sn   = ws + 12416;
    const float* Sa   = ws + 12480;

    const int tid = threadIdx.x;
    __shared__ float wv[4];
    __shared__ int   wi[4];
    __shared__ int   sIdx;

    float bv = 3.4e38f; int bi = 1 << 30;
    for (int k = tid; k < 4096; k += 256) {
        float v = dmat[k];
        if (v < bv) { bv = v; bi = k; }
    }
    #pragma unroll
    for (int off = 32; off > 0; off >>= 1) {
        float ov = __shfl_xor(bv, off);
        int   oi = __shfl_xor(bi, off);
        if (ov < bv || (ov == bv && oi < bi)) { bv = ov; bi = oi; }
    }
    if ((tid & 63) == 0) { wv[tid >> 6] = bv; wi[tid >> 6] = bi; }
    __syncthreads();
    if (tid == 0) {
        float fv = wv[0]; int fi = wi[0];
        for (int k = 1; k < 4; ++k)
            if (wv[k] < fv || (wv[k] == fv && wi[k] < fi)) { fv = wv[k]; fi = wi[k]; }
        sIdx = fi;
    }
    __syncthreads();
    const int idx = sIdx;
    const int mn = idx >> 6;
    const int ma = idx & 63;

    if (tid < 64) {
        float tn = 0.f, ta = 0.f;
        if (tid != mn)
            tn = Rn[tid] + Rn[mn] - 2.f * Gnn[tid*64 + mn]
               + 2e-6f * (Sn[tid] - Sn[mn]) + 409600.f * 1e-12f;
        if (tid != ma)
            ta = Ra[tid] + Ra[ma] - 2.f * Gaa[tid*64 + ma]
               + 2e-6f * (Sa[tid] - Sa[ma]) + 409600.f * 1e-12f;
        float s = tn + ta;
        #pragma unroll
        for (int off = 32; off > 0; off >>= 1) s += __shfl_xor(s, off);
        if (tid == 0)
            out[0] = 0.001f * dmat[idx] + s * (1.f / 12800.f);
    }
}

extern "C" void kernel_launch(void* const* d_in, const int* in_sizes, int n_in,
                              void* d_out, int out_size, void* d_ws, size_t ws_size,
                              hipStream_t stream)
{
    const float* feats = (const float*)d_in[0];
    float* out = (float*)d_out;
    float* ws  = (float*)d_ws;

    hipMemsetAsync(d_ws, 0, 12544 * sizeof(float), stream);
    cl_main<<<dim3(200), dim3(512), 0, stream>>>(feats, ws);
    cl_final<<<dim3(1), dim3(256), 0, stream>>>(ws, out);
}